// Round 2
// baseline (189.421 us; speedup 1.0000x reference)
//
#include <hip/hip_runtime.h>
#include <hip/hip_bf16.h>
#include <math.h>

typedef __attribute__((ext_vector_type(8))) short short8;
typedef __attribute__((ext_vector_type(4))) short short4_;
typedef __attribute__((ext_vector_type(4))) float f32x4;
typedef __attribute__((ext_vector_type(4))) unsigned int uint4_;

#define MFMA16(a, b, c) __builtin_amdgcn_mfma_f32_16x16x32_bf16((a), (b), (c), 0, 0, 0)

// workspace byte offsets
#define OFF_XTA   0
#define OFF_XTB   8388608
#define OFF_QBA   16777216
#define OFF_KBA   25165824
#define OFF_VBA   33554432
#define OFF_QBB   41943040
#define OFF_KBB   50331648
#define OFF_VBB   58720256
#define OFF_AOA   67108864
#define OFF_AOB   75497472
#define OFF_WQA   83886080
#define OFF_WQB   84279296
#define OFF_WOA   84672512
#define OFF_WOB   84803584

// fp32 -> bf16 round-to-nearest-even (scalar)
__device__ __forceinline__ short f2bf(float f) {
  union { float f; unsigned u; } v; v.f = f;
  unsigned r = v.u + 0x7fffu + ((v.u >> 16) & 1u);
  return (short)(r >> 16);
}

__device__ __forceinline__ float bf2f(short s) {
  union { float f; unsigned u; } v; v.u = ((unsigned)(unsigned short)s) << 16;
  return v.f;
}

// pack two fp32 -> 2x bf16 RNE in one v_cvt_pk_bf16_f32: a -> low, b -> high
__device__ __forceinline__ unsigned pk2bf(float a, float b) {
  union { __hip_bfloat162 h2; unsigned u; } cv;
  cv.h2 = __float22bfloat162_rn(float2{a, b});
  return cv.u;
}

// pack two fp32 -> 2x bf16 TRUNCATED (v_perm_b32), for attention P
__device__ __forceinline__ unsigned pktrunc(float a, float b) {
#if __has_builtin(__builtin_amdgcn_perm)
  return __builtin_amdgcn_perm(__builtin_bit_cast(unsigned, b),
                               __builtin_bit_cast(unsigned, a), 0x07060302u);
#else
  return (__builtin_bit_cast(unsigned, b) & 0xffff0000u) |
         (__builtin_bit_cast(unsigned, a) >> 16);
#endif
}

// Schraudolph-style exp2: full-rate (fma + cvt_i32), max rel err ~3%.
// Errors cancel in softmax: numerator and denominator use the same P.
__device__ __forceinline__ float approx_exp2(float x) {
  int i = (int)__builtin_fmaf(x, 8388608.0f, 1064991921.0f);
  return __builtin_bit_cast(float, i);
}

// async global -> LDS, 16 B per lane; LDS dest = base + lane*16 (base wave-uniform)
__device__ __forceinline__ void load_lds16(const void* g, void* l) {
  __builtin_amdgcn_global_load_lds((const __attribute__((address_space(1))) void*)g,
                                   (__attribute__((address_space(3))) void*)l, 16, 0, 0);
}

// scale(1/sqrt(256)) * log2(e), folded into Q values at the QKV GEMM epilogue
#define QSCALE 0.09016844005556f

// ---------------------------------------------------------------------------
// Prep: blocks 0..511 GroupNorm (A then B); blocks 512..767 weight convert.
// ---------------------------------------------------------------------------
__global__ __launch_bounds__(256) void prep_kernel(const float* __restrict__ xA,
                                                   const float* __restrict__ xB,
                                                   const float* __restrict__ gA,
                                                   const float* __restrict__ bA,
                                                   const float* __restrict__ gB,
                                                   const float* __restrict__ bB,
                                                   const float* __restrict__ wqA,
                                                   const float* __restrict__ wqB,
                                                   const float* __restrict__ woA,
                                                   const float* __restrict__ woB,
                                                   char* __restrict__ ws) {
  const int blk = blockIdx.x;
  const int t = threadIdx.x;
  if (blk >= 512) {  // weight convert
    int wb = blk - 512;
    const float* src; short* dst; int base;
    if (wb < 96) { src = wqA; dst = (short*)(ws + OFF_WQA); base = wb; }
    else if (wb < 192) { src = wqB; dst = (short*)(ws + OFF_WQB); base = wb - 96; }
    else if (wb < 224) { src = woA; dst = (short*)(ws + OFF_WOA); base = wb - 192; }
    else { src = woB; dst = (short*)(ws + OFF_WOB); base = wb - 224; }
    int idx = base * 2048 + t * 8;
    float4 a = *(const float4*)(src + idx);
    float4 b = *(const float4*)(src + idx + 4);
    uint4_ o;
    o[0] = pk2bf(a.x, a.y); o[1] = pk2bf(a.z, a.w);
    o[2] = pk2bf(b.x, b.y); o[3] = pk2bf(b.z, b.w);
    *(uint4_*)(dst + idx) = o;
    return;
  }
  const int br = blk >> 8, sub = blk & 255;
  const int b = sub >> 4, g = sub & 15;
  const float* x = br ? xB : xA;
  const float* gamma = br ? gB : gA;
  const float* beta = br ? bB : bA;
  short* Xt = (short*)(ws + (br ? OFF_XTB : OFF_XTA));
  const size_t base = (size_t)sub * 16384;
  const float4* xp = (const float4*)(x + base);
  float s = 0.f, q = 0.f;
  float4 vals[16];
  for (int i = 0; i < 16; ++i) {
    float4 v = xp[t + i * 256];  // channel g*16+i, s = 4t..4t+3
    vals[i] = v;
    s += v.x + v.y + v.z + v.w;
    q += v.x * v.x + v.y * v.y + v.z * v.z + v.w * v.w;
  }
  __shared__ float rs[256], rq[256];
  rs[t] = s; rq[t] = q;
  __syncthreads();
  for (int o = 128; o > 0; o >>= 1) {
    if (t < o) { rs[t] += rs[t + o]; rq[t] += rq[t + o]; }
    __syncthreads();
  }
  __shared__ float sh_mu, sh_inv;
  if (t == 0) {
    float mu = rs[0] * (1.f / 16384.f);
    float var = rq[0] * (1.f / 16384.f) - mu * mu;
    sh_mu = mu;
    sh_inv = rsqrtf(var + 1e-5f);
  }
  __syncthreads();
  const float mu = sh_mu, inv = sh_inv;
  unsigned td[4][8];
#pragma unroll
  for (int i = 0; i < 16; i += 2) {
    int c = (g << 4) + i;
    float ga0 = gamma[c] * inv, be0 = beta[c] - mu * ga0;
    float ga1 = gamma[c + 1] * inv, be1 = beta[c + 1] - mu * ga1;
    float4 v0 = vals[i], v1 = vals[i + 1];
    td[0][i >> 1] = pk2bf(v0.x * ga0 + be0, v1.x * ga1 + be1);
    td[1][i >> 1] = pk2bf(v0.y * ga0 + be0, v1.y * ga1 + be1);
    td[2][i >> 1] = pk2bf(v0.z * ga0 + be0, v1.z * ga1 + be1);
    td[3][i >> 1] = pk2bf(v0.w * ga0 + be0, v1.w * ga1 + be1);
  }
  short* orow = Xt + ((size_t)b * 1024 + 4 * t) * 256 + (g << 4);
#pragma unroll
  for (int j = 0; j < 4; ++j) {
    *(uint4_*)(orow + j * 256) = *(const uint4_*)&td[j][0];
    *(uint4_*)(orow + j * 256 + 8) = *(const uint4_*)&td[j][4];
  }
}

// ---------------------------------------------------------------------------
// QKV GEMM, both branches. Grid (nt=8, mt=6, z=b+16*br).
// ---------------------------------------------------------------------------
__global__ __launch_bounds__(256) void gemm_qkv_kernel(char* __restrict__ ws) {
  const int n0 = blockIdx.x * 128, m0 = blockIdx.y * 128;
  const int b = blockIdx.z & 15, br = blockIdx.z >> 4;
  const short* Wb = (const short*)(ws + (br ? OFF_WQB : OFF_WQA));
  const short* Xt = (const short*)(ws + (br ? OFF_XTB : OFF_XTA));
  short* Qb = (short*)(ws + (br ? OFF_QBB : OFF_QBA));
  short* Kb = Qb + 4194304;
  short* Vb = Qb + 8388608;
  const int t = threadIdx.x;
  __shared__ short As[128 * 64];
  __shared__ short Bs[128 * 64];
  const int w = t >> 6, lane = t & 63, l15 = lane & 15, quad = lane >> 4;
  const int wm = (w >> 1) * 64, wn = (w & 1) * 64;
  const f32x4 z4 = {0.f, 0.f, 0.f, 0.f};
  f32x4 acc[4][4];
  for (int i = 0; i < 4; i++)
    for (int j = 0; j < 4; j++) acc[i][j] = z4;

  const int srow = lane >> 3, cpos = lane & 7;
  const int swz = (cpos ^ srow) * 8;
  const short* wg = Wb + (size_t)(m0 + w * 32 + srow) * 256 + swz;
  const short* xg = Xt + ((size_t)b * 1024 + n0 + w * 32 + srow) * 256 + swz;
  short* lA = &As[(w * 32) * 64];
  short* lB = &Bs[(w * 32) * 64];

  for (int k0 = 0; k0 < 256; k0 += 64) {
    __syncthreads();
#pragma unroll
    for (int qq = 0; qq < 4; ++qq) {
      load_lds16(wg + (size_t)qq * 8 * 256 + k0, lA + qq * 8 * 64);
      load_lds16(xg + (size_t)qq * 8 * 256 + k0, lB + qq * 8 * 64);
    }
    __syncthreads();
#pragma unroll
    for (int s = 0; s < 2; ++s) {
      const int cc = ((s * 4 + quad) ^ (l15 & 7)) * 8;
      short8 af[4], bfb[4];
      for (int i = 0; i < 4; i++) af[i] = *(const short8*)&As[(wm + i * 16 + l15) * 64 + cc];
      for (int j = 0; j < 4; j++) bfb[j] = *(const short8*)&Bs[(wn + j * 16 + l15) * 64 + cc];
      for (int i = 0; i < 4; i++)
        for (int j = 0; j < 4; j++) acc[i][j] = MFMA16(af[i], bfb[j], acc[i][j]);
    }
  }
  for (int i = 0; i < 4; i++) {
    int mi = m0 + wm + i * 16;
    int h = mi / 96;
    int rr = mi - h * 96;
    if (rr < 64) {  // q or k: [b,h,s,d]
      short* dst = (rr < 32) ? Qb : Kb;
      const float mul = (rr < 32) ? QSCALE : 1.0f;
      const int dbase = (rr & 31) + quad * 4;
      const size_t rowb = ((size_t)b * 8 + h) * 1024;
      for (int j = 0; j < 4; j++) {
        int n = n0 + wn + j * 16 + l15;
        union { unsigned u[2]; short4_ s; } uv;
        uv.u[0] = pk2bf(acc[i][j][0] * mul, acc[i][j][1] * mul);
        uv.u[1] = pk2bf(acc[i][j][2] * mul, acc[i][j][3] * mul);
        *(short4_*)(dst + (rowb + n) * 32 + dbase) = uv.s;
      }
    } else {  // v: [b,h,d,s]
      const int dv = (rr - 64) + quad * 4;
      const size_t vb = (((size_t)b * 8 + h) * 32 + dv) * 1024;
      for (int j = 0; j < 4; j++) {
        int n = n0 + wn + j * 16 + l15;
        for (int r = 0; r < 4; r++) Vb[vb + (size_t)r * 1024 + n] = f2bf(acc[i][j][r]);
      }
    }
  }
}

// ---------------------------------------------------------------------------
// Flash cross-attention, both branches. Grid (b=16, h=8, z=qt+4*br).
// Block = 256 queries; wave owns FOUR 16-q blocks. 128-key K/V tiles,
// DOUBLE-BUFFERED in LDS (2x8KB K + 2x8KB V = 32KB): stage tile t+1 while
// computing tile t; counted s_waitcnt vmcnt(4) + raw s_barrier (loads stay
// in flight across the barrier — no vmcnt(0) drain in the loop); setprio(1)
// around the compute cluster. S^T=MFMA(A=K,B=Q); p=approx_exp2; P bf16-
// truncated (v_perm); l via ones-MFMA.
// ---------------------------------------------------------------------------
__global__ __launch_bounds__(256) void attn_kernel(char* __restrict__ ws) {
  const int b = blockIdx.x, h = blockIdx.y;
  const int qt = blockIdx.z & 3, br = blockIdx.z >> 2;
  // branch A output (br=0) uses Q from B, K/V from A; br=1 mirrored
  const short* Qb = (const short*)(ws + (br ? OFF_QBA : OFF_QBB));
  const short* Kb = (const short*)(ws + (br ? OFF_KBB : OFF_KBA));
  const short* Vb = Kb + 4194304;
  short* AO = (short*)(ws + (br ? OFF_AOB : OFF_AOA));
  const int t = threadIdx.x;
  const int w = t >> 6, lane = t & 63, l15 = lane & 15, quad = lane >> 4;
  const size_t hb = (size_t)(b * 8 + h);
  const f32x4 z4 = {0.f, 0.f, 0.f, 0.f};
  __shared__ short Ks[2][128 * 32];  // [sk][d], 16B-chunk col ^ ((sk>>1)&3)
  __shared__ short Vs[2][32 * 128];  // [dv][sk_loc], 16B-chunk col ^ (dv&15)

  const int q0 = qt * 256 + w * 64;
  short8 bq[4];
#pragma unroll
  for (int s = 0; s < 4; ++s)
    bq[s] = *(const short8*)(Qb + (hb * 1024 + q0 + s * 16 + l15) * 32 + quad * 8);
  const short* Kg = Kb + hb * 1024 * 32;
  const short* Vg = Vb + hb * 32 * 1024;

  short8 ones;
#pragma unroll
  for (int i = 0; i < 8; ++i) ones[i] = (short)0x3F80;  // bf16 1.0

  const int rk_off = lane >> 2;
  const int ck = lane & 3;
  const int rv_off = lane >> 4;
  const int cv = lane & 15;
  const int kread = l15 * 32 + ((quad ^ ((l15 >> 1) & 3)) * 8);

  f32x4 accO[4][2];  // [sq-block][dvt]
  f32x4 accL[4];
#pragma unroll
  for (int s = 0; s < 4; ++s) { accO[s][0] = z4; accO[s][1] = z4; accL[s] = z4; }

  // stage a 128-key tile (tile index tt) into buffer c: 4 loads/wave
  auto STAGE = [&](int c, int tt) {
    const int k0 = tt * 128;
#pragma unroll
    for (int p = 0; p < 2; ++p) {
      const int rk = (w * 2 + p) * 16 + rk_off;
      load_lds16(Kg + (size_t)(k0 + rk) * 32 + ((ck ^ ((rk >> 1) & 3)) * 8),
                 &Ks[c][(w * 2 + p) * 512]);
      const int rv = (w * 2 + p) * 4 + rv_off;
      load_lds16(Vg + (size_t)rv * 1024 + k0 + ((cv ^ (rv & 15)) * 8),
                 &Vs[c][(w * 2 + p) * 512]);
    }
  };

  auto COMPUTE = [&](int c) {
    const short* KsC = &Ks[c][0];
    const short* VsC = &Vs[c][0];
#pragma unroll
    for (int pr = 0; pr < 4; ++pr) {
      const short8 ak0 = *(const short8*)&KsC[(2 * pr) * 512 + kread];
      const short8 ak1 = *(const short8*)&KsC[(2 * pr + 1) * 512 + kread];
      // V operand (shared across the 4 sq-blocks)
      const int cg = pr * 4 + (quad >> 1);
      const int so = (quad & 1) * 4;
      union { short8 s; short4_ hh[2]; } bv[2];
#pragma unroll
      for (int dvt = 0; dvt < 2; ++dvt) {
        const int dvrow = (dvt * 16 + l15) * 128;
        bv[dvt].hh[0] = *(const short4_*)&VsC[dvrow + ((cg ^ l15) * 8) + so];
        bv[dvt].hh[1] = *(const short4_*)&VsC[dvrow + (((cg + 2) ^ l15) * 8) + so];
      }
#pragma unroll
      for (int s = 0; s < 4; ++s) {
        f32x4 st0 = MFMA16(ak0, bq[s], z4);
        f32x4 st1 = MFMA16(ak1, bq[s], z4);
        union { short8 s8; uint4_ u; } apv;
        float p0 = approx_exp2(st0[0]), p1 = approx_exp2(st0[1]);
        float p2 = approx_exp2(st0[2]), p3 = approx_exp2(st0[3]);
        float p4 = approx_exp2(st1[0]), p5 = approx_exp2(st1[1]);
        float p6 = approx_exp2(st1[2]), p7 = approx_exp2(st1[3]);
        apv.u[0] = pktrunc(p0, p1); apv.u[1] = pktrunc(p2, p3);
        apv.u[2] = pktrunc(p4, p5); apv.u[3] = pktrunc(p6, p7);
        accO[s][0] = MFMA16(apv.s8, bv[0].s, accO[s][0]);
        accO[s][1] = MFMA16(apv.s8, bv[1].s, accO[s][1]);
        accL[s] = MFMA16(apv.s8, ones, accL[s]);
      }
    }
  };

  STAGE(0, 0);
#pragma unroll
  for (int tt = 0; tt < 8; ++tt) {
    const int c = tt & 1;
    if (tt < 7) {
      STAGE(c ^ 1, tt + 1);
      // wait only until tile tt's 4 loads are done; tile tt+1's stay in flight
      asm volatile("s_waitcnt vmcnt(4)" ::: "memory");
    } else {
      asm volatile("s_waitcnt vmcnt(0)" ::: "memory");
    }
    __builtin_amdgcn_s_barrier();
    __builtin_amdgcn_sched_barrier(0);
    __builtin_amdgcn_s_setprio(1);
    COMPUTE(c);
    __builtin_amdgcn_s_setprio(0);
    __builtin_amdgcn_sched_barrier(0);
    // all waves done reading buf[c] before anyone stages tile tt+2 into it
    __builtin_amdgcn_s_barrier();
  }

#pragma unroll
  for (int s = 0; s < 4; ++s) {
    for (int r = 0; r < 4; r++) {
      float inv = 1.0f / accL[s][r];
      int sq = q0 + s * 16 + quad * 4 + r;
      short* orow = AO + ((size_t)b * 1024 + sq) * 256 + h * 32 + l15;
      orow[0] = f2bf(accO[s][0][r] * inv);
      orow[16] = f2bf(accO[s][1][r] * inv);
    }
  }
}

// ---------------------------------------------------------------------------
// Output GEMM, both branches: out[b,m,n] = sum_k Wob[m,k]*ao[b,n,k] + bias[m]
// + norm[b,m,n]. Grid (mt=2, nt=8, z=b+16*br).
// ---------------------------------------------------------------------------
__global__ __launch_bounds__(256) void gemm_out_kernel(char* __restrict__ ws,
                                                       const float* __restrict__ boutA,
                                                       const float* __restrict__ boutB,
                                                       float* __restrict__ outbase) {
  const int m0 = blockIdx.x * 128, n0 = blockIdx.y * 128;
  const int b = blockIdx.z & 15, br = blockIdx.z >> 4;
  const short* Wob = (const short*)(ws + (br ? OFF_WOB : OFF_WOA));
  const short* ao = (const short*)(ws + (br ? OFF_AOB : OFF_AOA));
  const float* bias = br ? boutB : boutA;
  const short* Xt = (const short*)(ws + (br ? OFF_XTB : OFF_XTA));
  float* out = outbase + (br ? 4194304 : 0);
  const int t = threadIdx.x;
  __shared__ short smem[128 * 64 * 2];
  short* As = smem;
  short* Bs = smem + 128 * 64;
  const int w = t >> 6, lane = t & 63, l15 = lane & 15, quad = lane >> 4;
  const int wm = (w >> 1) * 64, wn = (w & 1) * 64;
  const f32x4 z4 = {0.f, 0.f, 0.f, 0.f};
  f32x4 acc[4][4];
  for (int i = 0; i < 4; i++)
    for (int j = 0; j < 4; j++) acc[i][j] = z4;

  const int srow = lane >> 3, cpos = lane & 7;
  const int swz = (cpos ^ srow) * 8;
  const short* wg = Wob + (size_t)(m0 + w * 32 + srow) * 256 + swz;
  const short* xg = ao + ((size_t)b * 1024 + n0 + w * 32 + srow) * 256 + swz;
  short* lA = &As[(w * 32) * 64];
  short* lB = &Bs[(w * 32) * 64];

  for (int k0 = 0; k0 < 256; k0 += 64) {
    __syncthreads();
#pragma unroll
    for (int qq = 0; qq < 4; ++qq) {
      load_lds16(wg + (size_t)qq * 8 * 256 + k0, lA + qq * 8 * 64);
      load_lds16(xg + (size_t)qq * 8 * 256 + k0, lB + qq * 8 * 64);
    }
    __syncthreads();
#pragma unroll
    for (int s = 0; s < 2; ++s) {
      const int cc = ((s * 4 + quad) ^ (l15 & 7)) * 8;
      short8 af[4], bfb[4];
      for (int i = 0; i < 4; i++) af[i] = *(const short8*)&As[(wm + i * 16 + l15) * 64 + cc];
      for (int j = 0; j < 4; j++) bfb[j] = *(const short8*)&Bs[(wn + j * 16 + l15) * 64 + cc];
      for (int i = 0; i < 4; i++)
        for (int j = 0; j < 4; j++) acc[i][j] = MFMA16(af[i], bfb[j], acc[i][j]);
    }
  }

  __syncthreads();
  {
    const int rrow = lane >> 4, rc = lane & 15;
    for (int qq = 0; qq < 8; ++qq) {
      int row = w * 32 + qq * 4 + rrow;
      load_lds16(Xt + ((size_t)b * 1024 + n0 + row) * 256 + m0 + ((rc ^ (row & 15)) * 8),
                 &smem[(w * 32 + qq * 4) * 128]);
    }
  }
  __syncthreads();

  for (int i = 0; i < 4; i++)
    for (int j = 0; j < 4; j++) {
      int m = m0 + wm + i * 16 + quad * 4;
      int nl = wn + j * 16 + l15;
      int n = n0 + nl;
      size_t off = ((size_t)b * 256 + m) * 1024 + n;
      const int chunk = (wm >> 3) + i * 2 + (quad >> 1);
      short4_ rv = *(const short4_*)&smem[nl * 128 + ((chunk ^ (nl & 15)) * 8) + (quad & 1) * 4];
      for (int r = 0; r < 4; r++)
        out[off + (size_t)r * 1024] = acc[i][j][r] + bias[m + r] + bf2f(rv[r]);
    }
}

// ---------------------------------------------------------------------------
extern "C" void kernel_launch(void* const* d_in, const int* in_sizes, int n_in,
                              void* d_out, int out_size, void* d_ws, size_t ws_size,
                              hipStream_t stream) {
  const float* xA = (const float*)d_in[0];
  const float* xB = (const float*)d_in[1];
  const float* gA = (const float*)d_in[2];
  const float* bA = (const float*)d_in[3];
  const float* gB = (const float*)d_in[4];
  const float* bB = (const float*)d_in[5];
  const float* WqkvA = (const float*)d_in[6];
  const float* WqkvB = (const float*)d_in[7];
  const float* WoutA = (const float*)d_in[8];
  const float* boutA = (const float*)d_in[9];
  const float* WoutB = (const float*)d_in[10];
  const float* boutB = (const float*)d_in[11];
  float* out = (float*)d_out;
  char* ws = (char*)d_ws;

  prep_kernel<<<768, 256, 0, stream>>>(xA, xB, gA, bA, gB, bB,
                                       WqkvA, WqkvB, WoutA, WoutB, ws);
  gemm_qkv_kernel<<<dim3(8, 6, 32), 256, 0, stream>>>(ws);
  attn_kernel<<<dim3(16, 8, 8), 256, 0, stream>>>(ws);
  gemm_out_kernel<<<dim3(2, 8, 32), 256, 0, stream>>>(ws, boutA, boutB, out);
}

// Round 3
// 180.548 us; speedup vs baseline: 1.0491x; 1.0491x over previous
//
#include <hip/hip_runtime.h>
#include <hip/hip_bf16.h>
#include <math.h>

typedef __attribute__((ext_vector_type(8))) short short8;
typedef __attribute__((ext_vector_type(4))) short short4_;
typedef __attribute__((ext_vector_type(4))) float f32x4;
typedef __attribute__((ext_vector_type(4))) unsigned int uint4_;

#define MFMA16(a, b, c) __builtin_amdgcn_mfma_f32_16x16x32_bf16((a), (b), (c), 0, 0, 0)

// workspace byte offsets
#define OFF_XTA   0
#define OFF_XTB   8388608
#define OFF_QBA   16777216
#define OFF_KBA   25165824
#define OFF_VBA   33554432
#define OFF_QBB   41943040
#define OFF_KBB   50331648
#define OFF_VBB   58720256
#define OFF_AOA   67108864
#define OFF_AOB   75497472
#define OFF_WQA   83886080
#define OFF_WQB   84279296
#define OFF_WOA   84672512
#define OFF_WOB   84803584

// fp32 -> bf16 round-to-nearest-even (scalar)
__device__ __forceinline__ short f2bf(float f) {
  union { float f; unsigned u; } v; v.f = f;
  unsigned r = v.u + 0x7fffu + ((v.u >> 16) & 1u);
  return (short)(r >> 16);
}

__device__ __forceinline__ float bf2f(short s) {
  union { float f; unsigned u; } v; v.u = ((unsigned)(unsigned short)s) << 16;
  return v.f;
}

// pack two fp32 -> 2x bf16 RNE in one v_cvt_pk_bf16_f32: a -> low, b -> high
__device__ __forceinline__ unsigned pk2bf(float a, float b) {
  union { __hip_bfloat162 h2; unsigned u; } cv;
  cv.h2 = __float22bfloat162_rn(float2{a, b});
  return cv.u;
}

// pack two fp32 -> 2x bf16 TRUNCATED (v_perm_b32), for attention P
__device__ __forceinline__ unsigned pktrunc(float a, float b) {
#if __has_builtin(__builtin_amdgcn_perm)
  return __builtin_amdgcn_perm(__builtin_bit_cast(unsigned, b),
                               __builtin_bit_cast(unsigned, a), 0x07060302u);
#else
  return (__builtin_bit_cast(unsigned, b) & 0xffff0000u) |
         (__builtin_bit_cast(unsigned, a) >> 16);
#endif
}

// Schraudolph-style exp2: full-rate (fma + cvt_i32), max rel err ~3%.
// Errors cancel in softmax: numerator and denominator use the same P.
__device__ __forceinline__ float approx_exp2(float x) {
  int i = (int)__builtin_fmaf(x, 8388608.0f, 1064991921.0f);
  return __builtin_bit_cast(float, i);
}

// async global -> LDS, 16 B per lane; LDS dest = base + lane*16 (base wave-uniform)
__device__ __forceinline__ void load_lds16(const void* g, void* l) {
  __builtin_amdgcn_global_load_lds((const __attribute__((address_space(1))) void*)g,
                                   (__attribute__((address_space(3))) void*)l, 16, 0, 0);
}

// scale(1/sqrt(256)) * log2(e), folded into Q values at the QKV GEMM epilogue
#define QSCALE 0.09016844005556f

// ---------------------------------------------------------------------------
// Prep: blocks 0..511 GroupNorm (A then B); blocks 512..767 weight convert.
// ---------------------------------------------------------------------------
__global__ __launch_bounds__(256) void prep_kernel(const float* __restrict__ xA,
                                                   const float* __restrict__ xB,
                                                   const float* __restrict__ gA,
                                                   const float* __restrict__ bA,
                                                   const float* __restrict__ gB,
                                                   const float* __restrict__ bB,
                                                   const float* __restrict__ wqA,
                                                   const float* __restrict__ wqB,
                                                   const float* __restrict__ woA,
                                                   const float* __restrict__ woB,
                                                   char* __restrict__ ws) {
  const int blk = blockIdx.x;
  const int t = threadIdx.x;
  if (blk >= 512) {  // weight convert
    int wb = blk - 512;
    const float* src; short* dst; int base;
    if (wb < 96) { src = wqA; dst = (short*)(ws + OFF_WQA); base = wb; }
    else if (wb < 192) { src = wqB; dst = (short*)(ws + OFF_WQB); base = wb - 96; }
    else if (wb < 224) { src = woA; dst = (short*)(ws + OFF_WOA); base = wb - 192; }
    else { src = woB; dst = (short*)(ws + OFF_WOB); base = wb - 224; }
    int idx = base * 2048 + t * 8;
    float4 a = *(const float4*)(src + idx);
    float4 b = *(const float4*)(src + idx + 4);
    uint4_ o;
    o[0] = pk2bf(a.x, a.y); o[1] = pk2bf(a.z, a.w);
    o[2] = pk2bf(b.x, b.y); o[3] = pk2bf(b.z, b.w);
    *(uint4_*)(dst + idx) = o;
    return;
  }
  const int br = blk >> 8, sub = blk & 255;
  const int b = sub >> 4, g = sub & 15;
  const float* x = br ? xB : xA;
  const float* gamma = br ? gB : gA;
  const float* beta = br ? bB : bA;
  short* Xt = (short*)(ws + (br ? OFF_XTB : OFF_XTA));
  const size_t base = (size_t)sub * 16384;
  const float4* xp = (const float4*)(x + base);
  float s = 0.f, q = 0.f;
  float4 vals[16];
  for (int i = 0; i < 16; ++i) {
    float4 v = xp[t + i * 256];  // channel g*16+i, s = 4t..4t+3
    vals[i] = v;
    s += v.x + v.y + v.z + v.w;
    q += v.x * v.x + v.y * v.y + v.z * v.z + v.w * v.w;
  }
  __shared__ float rs[256], rq[256];
  rs[t] = s; rq[t] = q;
  __syncthreads();
  for (int o = 128; o > 0; o >>= 1) {
    if (t < o) { rs[t] += rs[t + o]; rq[t] += rq[t + o]; }
    __syncthreads();
  }
  __shared__ float sh_mu, sh_inv;
  if (t == 0) {
    float mu = rs[0] * (1.f / 16384.f);
    float var = rq[0] * (1.f / 16384.f) - mu * mu;
    sh_mu = mu;
    sh_inv = rsqrtf(var + 1e-5f);
  }
  __syncthreads();
  const float mu = sh_mu, inv = sh_inv;
  unsigned td[4][8];
#pragma unroll
  for (int i = 0; i < 16; i += 2) {
    int c = (g << 4) + i;
    float ga0 = gamma[c] * inv, be0 = beta[c] - mu * ga0;
    float ga1 = gamma[c + 1] * inv, be1 = beta[c + 1] - mu * ga1;
    float4 v0 = vals[i], v1 = vals[i + 1];
    td[0][i >> 1] = pk2bf(v0.x * ga0 + be0, v1.x * ga1 + be1);
    td[1][i >> 1] = pk2bf(v0.y * ga0 + be0, v1.y * ga1 + be1);
    td[2][i >> 1] = pk2bf(v0.z * ga0 + be0, v1.z * ga1 + be1);
    td[3][i >> 1] = pk2bf(v0.w * ga0 + be0, v1.w * ga1 + be1);
  }
  short* orow = Xt + ((size_t)b * 1024 + 4 * t) * 256 + (g << 4);
#pragma unroll
  for (int j = 0; j < 4; ++j) {
    *(uint4_*)(orow + j * 256) = *(const uint4_*)&td[j][0];
    *(uint4_*)(orow + j * 256 + 8) = *(const uint4_*)&td[j][4];
  }
}

// ---------------------------------------------------------------------------
// QKV GEMM, both branches. Grid (nt=8, mt=6, z=b+16*br).
// ---------------------------------------------------------------------------
__global__ __launch_bounds__(256) void gemm_qkv_kernel(char* __restrict__ ws) {
  const int n0 = blockIdx.x * 128, m0 = blockIdx.y * 128;
  const int b = blockIdx.z & 15, br = blockIdx.z >> 4;
  const short* Wb = (const short*)(ws + (br ? OFF_WQB : OFF_WQA));
  const short* Xt = (const short*)(ws + (br ? OFF_XTB : OFF_XTA));
  short* Qb = (short*)(ws + (br ? OFF_QBB : OFF_QBA));
  short* Kb = Qb + 4194304;
  short* Vb = Qb + 8388608;
  const int t = threadIdx.x;
  __shared__ short As[128 * 64];
  __shared__ short Bs[128 * 64];
  const int w = t >> 6, lane = t & 63, l15 = lane & 15, quad = lane >> 4;
  const int wm = (w >> 1) * 64, wn = (w & 1) * 64;
  const f32x4 z4 = {0.f, 0.f, 0.f, 0.f};
  f32x4 acc[4][4];
  for (int i = 0; i < 4; i++)
    for (int j = 0; j < 4; j++) acc[i][j] = z4;

  const int srow = lane >> 3, cpos = lane & 7;
  const int swz = (cpos ^ srow) * 8;
  const short* wg = Wb + (size_t)(m0 + w * 32 + srow) * 256 + swz;
  const short* xg = Xt + ((size_t)b * 1024 + n0 + w * 32 + srow) * 256 + swz;
  short* lA = &As[(w * 32) * 64];
  short* lB = &Bs[(w * 32) * 64];

  for (int k0 = 0; k0 < 256; k0 += 64) {
    __syncthreads();
#pragma unroll
    for (int qq = 0; qq < 4; ++qq) {
      load_lds16(wg + (size_t)qq * 8 * 256 + k0, lA + qq * 8 * 64);
      load_lds16(xg + (size_t)qq * 8 * 256 + k0, lB + qq * 8 * 64);
    }
    __syncthreads();
#pragma unroll
    for (int s = 0; s < 2; ++s) {
      const int cc = ((s * 4 + quad) ^ (l15 & 7)) * 8;
      short8 af[4], bfb[4];
      for (int i = 0; i < 4; i++) af[i] = *(const short8*)&As[(wm + i * 16 + l15) * 64 + cc];
      for (int j = 0; j < 4; j++) bfb[j] = *(const short8*)&Bs[(wn + j * 16 + l15) * 64 + cc];
      for (int i = 0; i < 4; i++)
        for (int j = 0; j < 4; j++) acc[i][j] = MFMA16(af[i], bfb[j], acc[i][j]);
    }
  }
  for (int i = 0; i < 4; i++) {
    int mi = m0 + wm + i * 16;
    int h = mi / 96;
    int rr = mi - h * 96;
    if (rr < 64) {  // q or k: [b,h,s,d]
      short* dst = (rr < 32) ? Qb : Kb;
      const float mul = (rr < 32) ? QSCALE : 1.0f;
      const int dbase = (rr & 31) + quad * 4;
      const size_t rowb = ((size_t)b * 8 + h) * 1024;
      for (int j = 0; j < 4; j++) {
        int n = n0 + wn + j * 16 + l15;
        union { unsigned u[2]; short4_ s; } uv;
        uv.u[0] = pk2bf(acc[i][j][0] * mul, acc[i][j][1] * mul);
        uv.u[1] = pk2bf(acc[i][j][2] * mul, acc[i][j][3] * mul);
        *(short4_*)(dst + (rowb + n) * 32 + dbase) = uv.s;
      }
    } else {  // v: [b,h,d,s]
      const int dv = (rr - 64) + quad * 4;
      const size_t vb = (((size_t)b * 8 + h) * 32 + dv) * 1024;
      for (int j = 0; j < 4; j++) {
        int n = n0 + wn + j * 16 + l15;
        for (int r = 0; r < 4; r++) Vb[vb + (size_t)r * 1024 + n] = f2bf(acc[i][j][r]);
      }
    }
  }
}

// ---------------------------------------------------------------------------
// Flash cross-attention, both branches. Grid (b=16, h=8, z=qt+4*br), 512 thr.
// Block = 256 queries over EIGHT waves (32 q each, 2 sq-blocks): halved
// per-wave state -> 3-4 blocks/CU resident, so one wave's staging drain and
// serial exp chains hide under other waves' MFMA/VALU (this kernel is
// VALU-throughput-bound: exp2+pack ~1.6x the MFMA issue time).
// 256-key LDS tiles via global_load_lds (XOR-swizzled), single-buffered,
// plain __syncthreads staging (verified round-1 structure).
// S^T=MFMA(A=K,B=Q); p=approx_exp2 (errors cancel num/denom);
// P bf16-truncated (v_perm); l via ones-MFMA.
// ---------------------------------------------------------------------------
__global__ __launch_bounds__(512) void attn_kernel(char* __restrict__ ws) {
  const int b = blockIdx.x, h = blockIdx.y;
  const int qt = blockIdx.z & 3, br = blockIdx.z >> 2;
  // branch A output (br=0) uses Q from B, K/V from A; br=1 mirrored
  const short* Qb = (const short*)(ws + (br ? OFF_QBA : OFF_QBB));
  const short* Kb = (const short*)(ws + (br ? OFF_KBB : OFF_KBA));
  const short* Vb = Kb + 4194304;
  short* AO = (short*)(ws + (br ? OFF_AOB : OFF_AOA));
  const int t = threadIdx.x;
  const int w = t >> 6, lane = t & 63, l15 = lane & 15, quad = lane >> 4;
  const size_t hb = (size_t)(b * 8 + h);
  const f32x4 z4 = {0.f, 0.f, 0.f, 0.f};
  __shared__ short Ks[256 * 32];  // [sk][d], 16B-chunk col ^ ((sk>>1)&3)
  __shared__ short Vs[32 * 256];  // [dv][sk_loc], 16B-chunk col ^ (dv&15)

  const int q0 = qt * 256 + w * 32;
  short8 bq[2];
#pragma unroll
  for (int s = 0; s < 2; ++s)
    bq[s] = *(const short8*)(Qb + (hb * 1024 + q0 + s * 16 + l15) * 32 + quad * 8);
  const short* Kg = Kb + hb * 1024 * 32;
  const short* Vg = Vb + hb * 32 * 1024;

  short8 ones;
#pragma unroll
  for (int i = 0; i < 8; ++i) ones[i] = (short)0x3F80;  // bf16 1.0

  const int rk_off = lane >> 2;
  const int ck = lane & 3;
  const int rv_off = lane >> 5;
  const int cv = lane & 31;
  const int kread = l15 * 32 + ((quad ^ ((l15 >> 1) & 3)) * 8);

  f32x4 accO[2][2];  // [sq-block][dvt]
  f32x4 accL[2];
#pragma unroll
  for (int s = 0; s < 2; ++s) { accO[s][0] = z4; accO[s][1] = z4; accL[s] = z4; }

  for (int k0 = 0; k0 < 1024; k0 += 256) {
    __syncthreads();
    // 16 staging units of 1KB each over 8 waves: u = w*2+p
    for (int p = 0; p < 2; ++p) {
      const int u = w * 2 + p;
      const int rk = u * 16 + rk_off;
      load_lds16(Kg + (size_t)(k0 + rk) * 32 + ((ck ^ ((rk >> 1) & 3)) * 8),
                 &Ks[u * 512]);
      const int rv = u * 2 + rv_off;
      load_lds16(Vg + (size_t)rv * 1024 + k0 + ((cv ^ (rv & 15)) * 8),
                 &Vs[u * 512]);
    }
    __syncthreads();

#pragma unroll
    for (int pr = 0; pr < 8; ++pr) {
      const short8 ak0 = *(const short8*)&Ks[(2 * pr) * 512 + kread];
      const short8 ak1 = *(const short8*)&Ks[(2 * pr + 1) * 512 + kread];
      // V operand (shared across the 2 sq-blocks)
      const int cg = pr * 4 + (quad >> 1);
      const int so = (quad & 1) * 4;
      union { short8 s; short4_ hh[2]; } bv[2];
#pragma unroll
      for (int dvt = 0; dvt < 2; ++dvt) {
        const int dvrow = (dvt * 16 + l15) * 256;
        bv[dvt].hh[0] = *(const short4_*)&Vs[dvrow + ((cg ^ l15) * 8) + so];
        bv[dvt].hh[1] = *(const short4_*)&Vs[dvrow + (((cg + 2) ^ l15) * 8) + so];
      }
#pragma unroll
      for (int s = 0; s < 2; ++s) {
        f32x4 st0 = MFMA16(ak0, bq[s], z4);
        f32x4 st1 = MFMA16(ak1, bq[s], z4);
        union { short8 s8; uint4_ u; } apv;
        float p0 = approx_exp2(st0[0]), p1 = approx_exp2(st0[1]);
        float p2 = approx_exp2(st0[2]), p3 = approx_exp2(st0[3]);
        float p4 = approx_exp2(st1[0]), p5 = approx_exp2(st1[1]);
        float p6 = approx_exp2(st1[2]), p7 = approx_exp2(st1[3]);
        apv.u[0] = pktrunc(p0, p1); apv.u[1] = pktrunc(p2, p3);
        apv.u[2] = pktrunc(p4, p5); apv.u[3] = pktrunc(p6, p7);
        accO[s][0] = MFMA16(apv.s8, bv[0].s, accO[s][0]);
        accO[s][1] = MFMA16(apv.s8, bv[1].s, accO[s][1]);
        accL[s] = MFMA16(apv.s8, ones, accL[s]);
      }
    }
  }

#pragma unroll
  for (int s = 0; s < 2; ++s) {
    for (int r = 0; r < 4; r++) {
      float inv = 1.0f / accL[s][r];
      int sq = q0 + s * 16 + quad * 4 + r;
      short* orow = AO + ((size_t)b * 1024 + sq) * 256 + h * 32 + l15;
      orow[0] = f2bf(accO[s][0][r] * inv);
      orow[16] = f2bf(accO[s][1][r] * inv);
    }
  }
}

// ---------------------------------------------------------------------------
// Output GEMM, both branches: out[b,m,n] = sum_k Wob[m,k]*ao[b,n,k] + bias[m]
// + norm[b,m,n]. Grid (mt=2, nt=8, z=b+16*br).
// ---------------------------------------------------------------------------
__global__ __launch_bounds__(256) void gemm_out_kernel(char* __restrict__ ws,
                                                       const float* __restrict__ boutA,
                                                       const float* __restrict__ boutB,
                                                       float* __restrict__ outbase) {
  const int m0 = blockIdx.x * 128, n0 = blockIdx.y * 128;
  const int b = blockIdx.z & 15, br = blockIdx.z >> 4;
  const short* Wob = (const short*)(ws + (br ? OFF_WOB : OFF_WOA));
  const short* ao = (const short*)(ws + (br ? OFF_AOB : OFF_AOA));
  const float* bias = br ? boutB : boutA;
  const short* Xt = (const short*)(ws + (br ? OFF_XTB : OFF_XTA));
  float* out = outbase + (br ? 4194304 : 0);
  const int t = threadIdx.x;
  __shared__ short smem[128 * 64 * 2];
  short* As = smem;
  short* Bs = smem + 128 * 64;
  const int w = t >> 6, lane = t & 63, l15 = lane & 15, quad = lane >> 4;
  const int wm = (w >> 1) * 64, wn = (w & 1) * 64;
  const f32x4 z4 = {0.f, 0.f, 0.f, 0.f};
  f32x4 acc[4][4];
  for (int i = 0; i < 4; i++)
    for (int j = 0; j < 4; j++) acc[i][j] = z4;

  const int srow = lane >> 3, cpos = lane & 7;
  const int swz = (cpos ^ srow) * 8;
  const short* wg = Wob + (size_t)(m0 + w * 32 + srow) * 256 + swz;
  const short* xg = ao + ((size_t)b * 1024 + n0 + w * 32 + srow) * 256 + swz;
  short* lA = &As[(w * 32) * 64];
  short* lB = &Bs[(w * 32) * 64];

  for (int k0 = 0; k0 < 256; k0 += 64) {
    __syncthreads();
#pragma unroll
    for (int qq = 0; qq < 4; ++qq) {
      load_lds16(wg + (size_t)qq * 8 * 256 + k0, lA + qq * 8 * 64);
      load_lds16(xg + (size_t)qq * 8 * 256 + k0, lB + qq * 8 * 64);
    }
    __syncthreads();
#pragma unroll
    for (int s = 0; s < 2; ++s) {
      const int cc = ((s * 4 + quad) ^ (l15 & 7)) * 8;
      short8 af[4], bfb[4];
      for (int i = 0; i < 4; i++) af[i] = *(const short8*)&As[(wm + i * 16 + l15) * 64 + cc];
      for (int j = 0; j < 4; j++) bfb[j] = *(const short8*)&Bs[(wn + j * 16 + l15) * 64 + cc];
      for (int i = 0; i < 4; i++)
        for (int j = 0; j < 4; j++) acc[i][j] = MFMA16(af[i], bfb[j], acc[i][j]);
    }
  }

  __syncthreads();
  {
    const int rrow = lane >> 4, rc = lane & 15;
    for (int qq = 0; qq < 8; ++qq) {
      int row = w * 32 + qq * 4 + rrow;
      load_lds16(Xt + ((size_t)b * 1024 + n0 + row) * 256 + m0 + ((rc ^ (row & 15)) * 8),
                 &smem[(w * 32 + qq * 4) * 128]);
    }
  }
  __syncthreads();

  for (int i = 0; i < 4; i++)
    for (int j = 0; j < 4; j++) {
      int m = m0 + wm + i * 16 + quad * 4;
      int nl = wn + j * 16 + l15;
      int n = n0 + nl;
      size_t off = ((size_t)b * 256 + m) * 1024 + n;
      const int chunk = (wm >> 3) + i * 2 + (quad >> 1);
      short4_ rv = *(const short4_*)&smem[nl * 128 + ((chunk ^ (nl & 15)) * 8) + (quad & 1) * 4];
      for (int r = 0; r < 4; r++)
        out[off + (size_t)r * 1024] = acc[i][j][r] + bias[m + r] + bf2f(rv[r]);
    }
}

// ---------------------------------------------------------------------------
extern "C" void kernel_launch(void* const* d_in, const int* in_sizes, int n_in,
                              void* d_out, int out_size, void* d_ws, size_t ws_size,
                              hipStream_t stream) {
  const float* xA = (const float*)d_in[0];
  const float* xB = (const float*)d_in[1];
  const float* gA = (const float*)d_in[2];
  const float* bA = (const float*)d_in[3];
  const float* gB = (const float*)d_in[4];
  const float* bB = (const float*)d_in[5];
  const float* WqkvA = (const float*)d_in[6];
  const float* WqkvB = (const float*)d_in[7];
  const float* WoutA = (const float*)d_in[8];
  const float* boutA = (const float*)d_in[9];
  const float* WoutB = (const float*)d_in[10];
  const float* boutB = (const float*)d_in[11];
  float* out = (float*)d_out;
  char* ws = (char*)d_ws;

  prep_kernel<<<768, 256, 0, stream>>>(xA, xB, gA, bA, gB, bB,
                                       WqkvA, WqkvB, WoutA, WoutB, ws);
  gemm_qkv_kernel<<<dim3(8, 6, 32), 256, 0, stream>>>(ws);
  attn_kernel<<<dim3(16, 8, 8), 512, 0, stream>>>(ws);
  gemm_out_kernel<<<dim3(2, 8, 32), 256, 0, stream>>>(ws, boutA, boutB, out);
}